// Round 1
// baseline (660.403 us; speedup 1.0000x reference)
//
#include <hip/hip_runtime.h>

typedef unsigned short u16;
typedef __attribute__((ext_vector_type(8))) short s16x8;
typedef __attribute__((ext_vector_type(4))) float f32x4;
typedef __attribute__((ext_vector_type(4))) u16   u16x4;
typedef __attribute__((ext_vector_type(4))) float f32x4v;

// ---- helpers ----
__device__ __forceinline__ u16 f2bf(float f) {
    unsigned u = __builtin_bit_cast(unsigned, f);
    unsigned r = (u + 0x7fffu + ((u >> 16) & 1u)) >> 16;
    return (u16)r;
}

__device__ __forceinline__ void gload_lds16(const u16* gp, u16* lp) {
    __builtin_amdgcn_global_load_lds(
        (const __attribute__((address_space(1))) unsigned*)(const void*)gp,
        (__attribute__((address_space(3))) unsigned*)(void*)lp,
        16, 0, 0);
}

// ---- f32 -> bf16 convert ----
__global__ void cvt_f32_bf16(const float* __restrict__ in, u16* __restrict__ out, int n4) {
    int stride = gridDim.x * blockDim.x;
    for (int i = blockIdx.x * blockDim.x + threadIdx.x; i < n4; i += stride) {
        f32x4 f = ((const f32x4*)in)[i];
        u16x4 o;
        o[0] = f2bf(f[0]); o[1] = f2bf(f[1]); o[2] = f2bf(f[2]); o[3] = f2bf(f[3]);
        ((u16x4*)out)[i] = o;
    }
}

// ---- GEMM: C[m][n] = sum_k A[m][k]*B[n][k]; M=8192 N=1024 K=1024 ----
// MODE 0: bf16 out, head-split [b,h,s,d], val=(acc+bias)*scale
// MODE 1: bf16 out, head-split transposed [b,h,d,s]
// MODE 2: f32 out, linear [m][n]
template<int MODE>
__global__ __launch_bounds__(256) void gemm_bt(const u16* __restrict__ A, const u16* __restrict__ B,
                                               const float* __restrict__ bias, void* __restrict__ outp,
                                               float scale) {
    __shared__ __align__(16) u16 As[128 * 64];
    __shared__ __align__(16) u16 Bs[128 * 64];
    const int tid  = threadIdx.x;
    const int w    = tid >> 6, lane = tid & 63;
    const int l15  = lane & 15, g = lane >> 4;
    const int wr   = w >> 1, wc = w & 1;
    const int bm0  = blockIdx.y * 128, bn0 = blockIdx.x * 128;

    f32x4 acc[4][4] = {};

    for (int kt = 0; kt < 16; ++kt) {
        __syncthreads();
#pragma unroll
        for (int i = 0; i < 4; ++i) {
            int c   = (w * 4 + i) * 64 + lane;   // 16B-chunk index 0..1023
            int row = c >> 3;
            int kc  = (c & 7) ^ (row & 7);       // pre-swizzled global source
            gload_lds16(A + (size_t)(bm0 + row) * 1024 + kt * 64 + kc * 8, &As[(w * 4 + i) * 512]);
            gload_lds16(B + (size_t)(bn0 + row) * 1024 + kt * 64 + kc * 8, &Bs[(w * 4 + i) * 512]);
        }
        asm volatile("s_waitcnt vmcnt(0)" ::: "memory");
        __syncthreads();

#pragma unroll
        for (int kk = 0; kk < 2; ++kk) {
            s16x8 af[4], bf_[4];
#pragma unroll
            for (int mi = 0; mi < 4; ++mi) {
                int row = wr * 64 + mi * 16 + l15;
                af[mi] = *(const s16x8*)&As[row * 64 + (((kk * 4 + g) ^ (row & 7)) << 3)];
            }
#pragma unroll
            for (int ni = 0; ni < 4; ++ni) {
                int row = wc * 64 + ni * 16 + l15;
                bf_[ni] = *(const s16x8*)&Bs[row * 64 + (((kk * 4 + g) ^ (row & 7)) << 3)];
            }
#pragma unroll
            for (int mi = 0; mi < 4; ++mi)
#pragma unroll
                for (int ni = 0; ni < 4; ++ni)
                    acc[mi][ni] = __builtin_amdgcn_mfma_f32_16x16x32_bf16(af[mi], bf_[ni], acc[mi][ni], 0, 0, 0);
        }
    }

#pragma unroll
    for (int mi = 0; mi < 4; ++mi) {
#pragma unroll
        for (int ni = 0; ni < 4; ++ni) {
            int ncol = bn0 + wc * 64 + ni * 16 + l15;
            float bv = bias[ncol];
#pragma unroll
            for (int r = 0; r < 4; ++r) {
                int m   = bm0 + wr * 64 + mi * 16 + g * 4 + r;
                float v = (acc[mi][ni][r] + bv) * scale;
                if constexpr (MODE == 0) {
                    int b_ = m >> 11, s = m & 2047, h = ncol >> 6, d = ncol & 63;
                    ((u16*)outp)[(((size_t)(b_ * 16 + h)) * 2048 + s) * 64 + d] = f2bf(v);
                } else if constexpr (MODE == 1) {
                    int b_ = m >> 11, s = m & 2047, h = ncol >> 6, d = ncol & 63;
                    ((u16*)outp)[(((size_t)(b_ * 16 + h)) * 64 + d) * 2048 + s] = f2bf(v);
                } else {
                    ((float*)outp)[(size_t)m * 1024 + ncol] = v;
                }
            }
        }
    }
}

// ---- flash attention: Q[bh][s][d] (pre-scaled), K[bh][s][d], VT[bh][d][s] -> concat bf16 [b][s][e] ----
__global__ __launch_bounds__(256) void attn_kernel(const u16* __restrict__ Q, const u16* __restrict__ K,
                                                   const u16* __restrict__ VT, u16* __restrict__ C) {
    __shared__ __align__(16) u16 Plds[4][1024];   // per-wave 16x64 bf16, XOR-swizzled
    const int tid = threadIdx.x;
    const int w   = tid >> 6, lane = tid & 63;
    const int l15 = lane & 15, g = lane >> 4;
    const int bh  = blockIdx.x >> 5;
    const int qt  = blockIdx.x & 31;
    const u16* Qb = Q  + (size_t)bh * 2048 * 64;
    const u16* Kb = K  + (size_t)bh * 2048 * 64;
    const u16* Vb = VT + (size_t)bh * 64 * 2048;
    const int q0  = qt * 64 + w * 16;

    s16x8 aq[2];
#pragma unroll
    for (int kk = 0; kk < 2; ++kk)
        aq[kk] = *(const s16x8*)&Qb[(size_t)(q0 + l15) * 64 + kk * 32 + g * 8];

    float m_[4], l_[4];
    f32x4 accO[4] = {};
#pragma unroll
    for (int r = 0; r < 4; ++r) { m_[r] = -1e30f; l_[r] = 0.f; }

    for (int kt = 0; kt < 32; ++kt) {
        const int kbase = kt * 64;
        f32x4 sc[4];
#pragma unroll
        for (int j = 0; j < 4; ++j) {
            f32x4 z = {};
#pragma unroll
            for (int kk = 0; kk < 2; ++kk) {
                s16x8 bk = *(const s16x8*)&Kb[(size_t)(kbase + j * 16 + l15) * 64 + kk * 32 + g * 8];
                z = __builtin_amdgcn_mfma_f32_16x16x32_bf16(aq[kk], bk, z, 0, 0, 0);
            }
            sc[j] = z;
        }

        float alpha[4], p[4][4];
#pragma unroll
        for (int r = 0; r < 4; ++r) {
            float t = fmaxf(fmaxf(sc[0][r], sc[1][r]), fmaxf(sc[2][r], sc[3][r]));
#pragma unroll
            for (int msk = 1; msk < 16; msk <<= 1) t = fmaxf(t, __shfl_xor(t, msk));
            float mn = fmaxf(m_[r], t);
            alpha[r] = __expf(m_[r] - mn);
            m_[r]    = mn;
            float ps = 0.f;
#pragma unroll
            for (int j = 0; j < 4; ++j) { p[j][r] = __expf(sc[j][r] - mn); ps += p[j][r]; }
#pragma unroll
            for (int msk = 1; msk < 16; msk <<= 1) ps += __shfl_xor(ps, msk);
            l_[r] = l_[r] * alpha[r] + ps;
        }

        // P -> LDS (bf16, swizzled), per-wave private region
#pragma unroll
        for (int j = 0; j < 4; ++j) {
            int colc = (j * 16 + l15) >> 3;
            int coff = l15 & 7;
#pragma unroll
            for (int r = 0; r < 4; ++r) {
                int row = g * 4 + r;
                Plds[w][row * 64 + ((colc ^ (row & 7)) << 3) + coff] = f2bf(p[j][r]);
            }
        }

#pragma unroll
        for (int jd = 0; jd < 4; ++jd)
#pragma unroll
            for (int r = 0; r < 4; ++r) accO[jd][r] *= alpha[r];

        s16x8 pf[2];
#pragma unroll
        for (int kk = 0; kk < 2; ++kk)
            pf[kk] = *(const s16x8*)&Plds[w][l15 * 64 + (((kk * 4 + g) ^ (l15 & 7)) << 3)];
#pragma unroll
        for (int jd = 0; jd < 4; ++jd) {
#pragma unroll
            for (int kk = 0; kk < 2; ++kk) {
                s16x8 bv = *(const s16x8*)&Vb[(size_t)(jd * 16 + l15) * 2048 + kbase + kk * 32 + g * 8];
                accO[jd] = __builtin_amdgcn_mfma_f32_16x16x32_bf16(pf[kk], bv, accO[jd], 0, 0, 0);
            }
        }
    }

    const int b_ = bh >> 4, h = bh & 15;
#pragma unroll
    for (int r = 0; r < 4; ++r) {
        float inv = 1.0f / l_[r];
        int s     = q0 + g * 4 + r;
#pragma unroll
        for (int jd = 0; jd < 4; ++jd) {
            float v = accO[jd][r] * inv;
            C[((size_t)(b_ * 2048 + s)) * 1024 + h * 64 + jd * 16 + l15] = f2bf(v);
        }
    }
}

extern "C" void kernel_launch(void* const* d_in, const int* in_sizes, int n_in,
                              void* d_out, int out_size, void* d_ws, size_t ws_size,
                              hipStream_t stream) {
    const float* H  = (const float*)d_in[0];
    const float* Wq = (const float*)d_in[1];
    const float* bq = (const float*)d_in[2];
    const float* Wk = (const float*)d_in[3];
    const float* bk = (const float*)d_in[4];
    const float* Wv = (const float*)d_in[5];
    const float* bv = (const float*)d_in[6];
    const float* Wo = (const float*)d_in[7];
    const float* bo = (const float*)d_in[8];

    char*  ws  = (char*)d_ws;
    size_t off = 0;
    auto alloc = [&](size_t elems) { u16* p = (u16*)(ws + off); off += elems * 2; return p; };
    u16* Hb  = alloc((size_t)8192 * 1024);
    u16* Wqb = alloc((size_t)1024 * 1024);
    u16* Wkb = alloc((size_t)1024 * 1024);
    u16* Wvb = alloc((size_t)1024 * 1024);
    u16* Wob = alloc((size_t)1024 * 1024);
    u16* Qs  = alloc((size_t)8192 * 1024);
    u16* Ks  = alloc((size_t)8192 * 1024);
    u16* VTs = alloc((size_t)8192 * 1024);
    u16* Cc  = alloc((size_t)8192 * 1024);

    cvt_f32_bf16<<<2048, 256, 0, stream>>>(H,  Hb,  8192 * 1024 / 4);
    cvt_f32_bf16<<<1024, 256, 0, stream>>>(Wq, Wqb, 1024 * 1024 / 4);
    cvt_f32_bf16<<<1024, 256, 0, stream>>>(Wk, Wkb, 1024 * 1024 / 4);
    cvt_f32_bf16<<<1024, 256, 0, stream>>>(Wv, Wvb, 1024 * 1024 / 4);
    cvt_f32_bf16<<<1024, 256, 0, stream>>>(Wo, Wob, 1024 * 1024 / 4);

    dim3 gg(8, 64);
    gemm_bt<0><<<gg, 256, 0, stream>>>(Hb, Wqb, bq, (void*)Qs,  0.125f);
    gemm_bt<0><<<gg, 256, 0, stream>>>(Hb, Wkb, bk, (void*)Ks,  1.0f);
    gemm_bt<1><<<gg, 256, 0, stream>>>(Hb, Wvb, bv, (void*)VTs, 1.0f);

    attn_kernel<<<2048, 256, 0, stream>>>(Qs, Ks, VTs, Cc);

    gemm_bt<2><<<gg, 256, 0, stream>>>(Cc, Wob, bo, d_out, 1.0f);
}

// Round 2
// 355.477 us; speedup vs baseline: 1.8578x; 1.8578x over previous
//
#include <hip/hip_runtime.h>

typedef unsigned short u16;
typedef unsigned int u32;
typedef __attribute__((ext_vector_type(8))) short s16x8;
typedef __attribute__((ext_vector_type(4))) float f32x4;
typedef __attribute__((ext_vector_type(4))) u16   u16x4;
typedef __attribute__((ext_vector_type(2))) u32   u32x2;

// ---- helpers ----
__device__ __forceinline__ u16 f2bf(float f) {
    unsigned u = __builtin_bit_cast(unsigned, f);
    unsigned r = (u + 0x7fffu + ((u >> 16) & 1u)) >> 16;
    return (u16)r;
}

__device__ __forceinline__ void gload_lds16(const u16* gp, u16* lp) {
    __builtin_amdgcn_global_load_lds(
        (const __attribute__((address_space(1))) unsigned*)(const void*)gp,
        (__attribute__((address_space(3))) unsigned*)(void*)lp,
        16, 0, 0);
}

// ---- f32 -> bf16 convert ----
__global__ void cvt_f32_bf16(const float* __restrict__ in, u16* __restrict__ out, int n4) {
    int stride = gridDim.x * blockDim.x;
    for (int i = blockIdx.x * blockDim.x + threadIdx.x; i < n4; i += stride) {
        f32x4 f = ((const f32x4*)in)[i];
        u16x4 o;
        o[0] = f2bf(f[0]); o[1] = f2bf(f[1]); o[2] = f2bf(f[2]); o[3] = f2bf(f[3]);
        ((u16x4*)out)[i] = o;
    }
}

// ---- GEMM: C[m][n] = sum_k A[m][k]*B[n][k]; M=8192 N=1024 K=1024 ----
template<int MODE>
__global__ __launch_bounds__(256) void gemm_bt(const u16* __restrict__ A, const u16* __restrict__ B,
                                               const float* __restrict__ bias, void* __restrict__ outp,
                                               float scale) {
    __shared__ __align__(16) u16 As[128 * 64];
    __shared__ __align__(16) u16 Bs[128 * 64];
    const int tid  = threadIdx.x;
    const int w    = tid >> 6, lane = tid & 63;
    const int l15  = lane & 15, g = lane >> 4;
    const int wr   = w >> 1, wc = w & 1;
    const int bm0  = blockIdx.y * 128, bn0 = blockIdx.x * 128;

    f32x4 acc[4][4] = {};

    for (int kt = 0; kt < 16; ++kt) {
        __syncthreads();
#pragma unroll
        for (int i = 0; i < 4; ++i) {
            int c   = (w * 4 + i) * 64 + lane;
            int row = c >> 3;
            int kc  = (c & 7) ^ (row & 7);
            gload_lds16(A + (size_t)(bm0 + row) * 1024 + kt * 64 + kc * 8, &As[(w * 4 + i) * 512]);
            gload_lds16(B + (size_t)(bn0 + row) * 1024 + kt * 64 + kc * 8, &Bs[(w * 4 + i) * 512]);
        }
        asm volatile("s_waitcnt vmcnt(0)" ::: "memory");
        __syncthreads();

#pragma unroll
        for (int kk = 0; kk < 2; ++kk) {
            s16x8 af[4], bf_[4];
#pragma unroll
            for (int mi = 0; mi < 4; ++mi) {
                int row = wr * 64 + mi * 16 + l15;
                af[mi] = *(const s16x8*)&As[row * 64 + (((kk * 4 + g) ^ (row & 7)) << 3)];
            }
#pragma unroll
            for (int ni = 0; ni < 4; ++ni) {
                int row = wc * 64 + ni * 16 + l15;
                bf_[ni] = *(const s16x8*)&Bs[row * 64 + (((kk * 4 + g) ^ (row & 7)) << 3)];
            }
#pragma unroll
            for (int mi = 0; mi < 4; ++mi)
#pragma unroll
                for (int ni = 0; ni < 4; ++ni)
                    acc[mi][ni] = __builtin_amdgcn_mfma_f32_16x16x32_bf16(af[mi], bf_[ni], acc[mi][ni], 0, 0, 0);
        }
    }

#pragma unroll
    for (int mi = 0; mi < 4; ++mi) {
#pragma unroll
        for (int ni = 0; ni < 4; ++ni) {
            int ncol = bn0 + wc * 64 + ni * 16 + l15;
            float bv = bias[ncol];
#pragma unroll
            for (int r = 0; r < 4; ++r) {
                int m   = bm0 + wr * 64 + mi * 16 + g * 4 + r;
                float v = (acc[mi][ni][r] + bv) * scale;
                if constexpr (MODE == 0) {
                    int b_ = m >> 11, s = m & 2047, h = ncol >> 6, d = ncol & 63;
                    ((u16*)outp)[(((size_t)(b_ * 16 + h)) * 2048 + s) * 64 + d] = f2bf(v);
                } else if constexpr (MODE == 1) {
                    int b_ = m >> 11, s = m & 2047, h = ncol >> 6, d = ncol & 63;
                    ((u16*)outp)[(((size_t)(b_ * 16 + h)) * 64 + d) * 2048 + s] = f2bf(v);
                } else {
                    ((float*)outp)[(size_t)m * 1024 + ncol] = v;
                }
            }
        }
    }
}

// ---- flash attention, swapped-operand form ----
// Q[bh][s][d] pre-scaled by log2e/8, K[bh][s][d], VT[bh][d][s] -> concat bf16 [b][s][e]
__global__ __launch_bounds__(256) void attn_kernel(const u16* __restrict__ Q, const u16* __restrict__ K,
                                                   const u16* __restrict__ VT, u16* __restrict__ C) {
    __shared__ __align__(16) u16 Ks[64 * 64];
    __shared__ __align__(16) u16 Vs[64 * 64];
    __shared__ __align__(16) u16 Ps[4][16 * 64];
    const int tid = threadIdx.x;
    const int w   = tid >> 6, lane = tid & 63;
    const int l15 = lane & 15, g = lane >> 4;
    const int bh  = blockIdx.x >> 5;
    const int qt  = blockIdx.x & 31;
    const u16* Qb = Q  + (size_t)bh * 2048 * 64;
    const u16* Kb = K  + (size_t)bh * 2048 * 64;
    const u16* Vb = VT + (size_t)bh * 64 * 2048;
    const int q0  = qt * 64 + w * 16;

    // Q rows as B-fragments (col=q): b[i] = Q[q=l15][k=g*8+i (+32*kk)]
    s16x8 bq[2];
#pragma unroll
    for (int kk = 0; kk < 2; ++kk)
        bq[kk] = *(const s16x8*)&Qb[(size_t)(q0 + l15) * 64 + kk * 32 + g * 8];

    float m_ = -1e30f, l_ = 0.f;
    f32x4 accO[4] = {};   // accO[jd][r] = O[q=l15][d=jd*16+g*4+r]

    for (int kt = 0; kt < 32; ++kt) {
        const int kbase = kt * 64;
        __syncthreads();
        // stage K tile [64 keys][64 d] and VT tile [64 d][64 keys], pre-swizzled source
#pragma unroll
        for (int i = 0; i < 2; ++i) {
            int c  = w * 128 + i * 64 + lane;
            int rt = c >> 3;
            int cc = (c & 7) ^ (rt & 7);
            gload_lds16(Kb + (size_t)(kbase + rt) * 64 + cc * 8, &Ks[(w * 128 + i * 64) * 8]);
            gload_lds16(Vb + (size_t)rt * 2048 + kbase + cc * 8, &Vs[(w * 128 + i * 64) * 8]);
        }
        asm volatile("s_waitcnt vmcnt(0)" ::: "memory");
        __syncthreads();

        // S^T = K . Q^T : lane holds S[q=l15][k = kj*16 + g*4 + r]
        f32x4 sc[4];
#pragma unroll
        for (int kj = 0; kj < 4; ++kj) {
            f32x4 z = {};
#pragma unroll
            for (int kk = 0; kk < 2; ++kk) {
                int row  = kj * 16 + l15;
                s16x8 ak = *(const s16x8*)&Ks[row * 64 + (((kk * 4 + g) ^ (l15 & 7)) << 3)];
                z = __builtin_amdgcn_mfma_f32_16x16x32_bf16(ak, bq[kk], z, 0, 0, 0);
            }
            sc[kj] = z;
        }

        // online softmax, row q=l15 lane-local (exp2 domain)
        float t0 = fmaxf(fmaxf(sc[0][0], sc[0][1]), fmaxf(sc[0][2], sc[0][3]));
        float t1 = fmaxf(fmaxf(sc[1][0], sc[1][1]), fmaxf(sc[1][2], sc[1][3]));
        float t2 = fmaxf(fmaxf(sc[2][0], sc[2][1]), fmaxf(sc[2][2], sc[2][3]));
        float t3 = fmaxf(fmaxf(sc[3][0], sc[3][1]), fmaxf(sc[3][2], sc[3][3]));
        float t  = fmaxf(fmaxf(t0, t1), fmaxf(t2, t3));
        t = fmaxf(t, __shfl_xor(t, 16));
        t = fmaxf(t, __shfl_xor(t, 32));
        float mn    = fmaxf(m_, t);
        float alpha = __builtin_amdgcn_exp2f(m_ - mn);
        m_ = mn;
        float p[4][4], ps = 0.f;
#pragma unroll
        for (int kj = 0; kj < 4; ++kj)
#pragma unroll
            for (int r = 0; r < 4; ++r) {
                p[kj][r] = __builtin_amdgcn_exp2f(sc[kj][r] - mn);
                ps += p[kj][r];
            }
        ps += __shfl_xor(ps, 16);
        ps += __shfl_xor(ps, 32);
        l_ = l_ * alpha + ps;

        // P -> LDS (per-wave private), 4x b64 packed writes, chunk XOR swizzle
#pragma unroll
        for (int kj = 0; kj < 4; ++kj) {
            int c  = kj * 4 + g;
            int cs = c ^ ((l15 & 7) << 1);
            u32x2 v;
            v[0] = (u32)f2bf(p[kj][0]) | ((u32)f2bf(p[kj][1]) << 16);
            v[1] = (u32)f2bf(p[kj][2]) | ((u32)f2bf(p[kj][3]) << 16);
            *(u32x2*)&Ps[w][l15 * 64 + cs * 4] = v;
        }

        // rescale accumulator (alpha lane-local)
#pragma unroll
        for (int jd = 0; jd < 4; ++jd)
#pragma unroll
            for (int r = 0; r < 4; ++r) accO[jd][r] *= alpha;

        // P fragments back (B-frag pattern: row q=l15, k-slice)
        s16x8 pf[2];
#pragma unroll
        for (int kk = 0; kk < 2; ++kk) {
            int c0 = (kk * 8 + g * 2) ^ ((l15 & 7) << 1);
            pf[kk] = *(const s16x8*)&Ps[w][l15 * 64 + c0 * 4];
        }

        // O^T += V^T . P^T : accO col=q=l15, row=d
#pragma unroll
        for (int jd = 0; jd < 4; ++jd) {
#pragma unroll
            for (int kk = 0; kk < 2; ++kk) {
                int row  = jd * 16 + l15;
                s16x8 av = *(const s16x8*)&Vs[row * 64 + (((kk * 4 + g) ^ (l15 & 7)) << 3)];
                accO[jd] = __builtin_amdgcn_mfma_f32_16x16x32_bf16(av, pf[kk], accO[jd], 0, 0, 0);
            }
        }
    }

    const int b_ = bh >> 4, h = bh & 15;
    const int s  = q0 + l15;
    float inv    = 1.0f / l_;
#pragma unroll
    for (int jd = 0; jd < 4; ++jd) {
        u32x2 v;
        v[0] = (u32)f2bf(accO[jd][0] * inv) | ((u32)f2bf(accO[jd][1] * inv) << 16);
        v[1] = (u32)f2bf(accO[jd][2] * inv) | ((u32)f2bf(accO[jd][3] * inv) << 16);
        *(u32x2*)&C[((size_t)(b_ * 2048 + s)) * 1024 + h * 64 + jd * 16 + g * 4] = v;
    }
}

extern "C" void kernel_launch(void* const* d_in, const int* in_sizes, int n_in,
                              void* d_out, int out_size, void* d_ws, size_t ws_size,
                              hipStream_t stream) {
    const float* H  = (const float*)d_in[0];
    const float* Wq = (const float*)d_in[1];
    const float* bq = (const float*)d_in[2];
    const float* Wk = (const float*)d_in[3];
    const float* bk = (const float*)d_in[4];
    const float* Wv = (const float*)d_in[5];
    const float* bv = (const float*)d_in[6];
    const float* Wo = (const float*)d_in[7];
    const float* bo = (const float*)d_in[8];

    char*  ws  = (char*)d_ws;
    size_t off = 0;
    auto alloc = [&](size_t elems) { u16* p = (u16*)(ws + off); off += elems * 2; return p; };
    u16* Hb  = alloc((size_t)8192 * 1024);
    u16* Wqb = alloc((size_t)1024 * 1024);
    u16* Wkb = alloc((size_t)1024 * 1024);
    u16* Wvb = alloc((size_t)1024 * 1024);
    u16* Wob = alloc((size_t)1024 * 1024);
    u16* Qs  = alloc((size_t)8192 * 1024);
    u16* Ks  = alloc((size_t)8192 * 1024);
    u16* VTs = alloc((size_t)8192 * 1024);
    u16* Cc  = alloc((size_t)8192 * 1024);

    cvt_f32_bf16<<<2048, 256, 0, stream>>>(H,  Hb,  8192 * 1024 / 4);
    cvt_f32_bf16<<<1024, 256, 0, stream>>>(Wq, Wqb, 1024 * 1024 / 4);
    cvt_f32_bf16<<<1024, 256, 0, stream>>>(Wk, Wkb, 1024 * 1024 / 4);
    cvt_f32_bf16<<<1024, 256, 0, stream>>>(Wv, Wvb, 1024 * 1024 / 4);
    cvt_f32_bf16<<<1024, 256, 0, stream>>>(Wo, Wob, 1024 * 1024 / 4);

    dim3 gg(8, 64);
    // Q pre-scaled by (1/8)*log2(e) so softmax runs in exp2 domain
    gemm_bt<0><<<gg, 256, 0, stream>>>(Hb, Wqb, bq, (void*)Qs,  0.18033688011112042f);
    gemm_bt<0><<<gg, 256, 0, stream>>>(Hb, Wkb, bk, (void*)Ks,  1.0f);
    gemm_bt<1><<<gg, 256, 0, stream>>>(Hb, Wvb, bv, (void*)VTs, 1.0f);

    attn_kernel<<<2048, 256, 0, stream>>>(Qs, Ks, VTs, Cc);

    gemm_bt<2><<<gg, 256, 0, stream>>>(Cc, Wob, bo, d_out, 1.0f);
}

// Round 5
// 337.698 us; speedup vs baseline: 1.9556x; 1.0526x over previous
//
#include <hip/hip_runtime.h>

typedef unsigned short u16;
typedef unsigned int u32;
typedef __attribute__((ext_vector_type(8))) short s16x8;
typedef __attribute__((ext_vector_type(4))) float f32x4;
typedef __attribute__((ext_vector_type(4))) u16   u16x4;
typedef __attribute__((ext_vector_type(2))) u32   u32x2;

// ---- helpers ----
__device__ __forceinline__ u16 f2bf(float f) {
    unsigned u = __builtin_bit_cast(unsigned, f);
    unsigned r = (u + 0x7fffu + ((u >> 16) & 1u)) >> 16;
    return (u16)r;
}

__device__ __forceinline__ u32 cvt_pk_bf16(float a, float b) {
    u32 r;
    asm("v_cvt_pk_bf16_f32 %0, %1, %2" : "=v"(r) : "v"(a), "v"(b));
    return r;
}

__device__ __forceinline__ void gload_lds16(const u16* gp, u16* lp) {
    __builtin_amdgcn_global_load_lds(
        (const __attribute__((address_space(1))) unsigned*)(const void*)gp,
        (__attribute__((address_space(3))) unsigned*)(void*)lp,
        16, 0, 0);
}

// ---- fused f32 -> bf16 convert: H (2M quads) + 4 weights (256K quads each) ----
__global__ __launch_bounds__(256) void cvt_all(const float* __restrict__ H,
        const float* __restrict__ Wq, const float* __restrict__ Wk,
        const float* __restrict__ Wv, const float* __restrict__ Wo,
        u16* __restrict__ Hb, u16* __restrict__ Wqb, u16* __restrict__ Wkb,
        u16* __restrict__ Wvb, u16* __restrict__ Wob) {
    int i = blockIdx.x * blockDim.x + threadIdx.x;   // quad index
    const float* s; u16* d; int o;
    if (i < 2097152) { s = H; d = Hb; o = i; }
    else {
        int j = i - 2097152;
        int a = j >> 18; o = j & 262143;
        s = a == 0 ? Wq : a == 1 ? Wk : a == 2 ? Wv : Wo;
        d = a == 0 ? Wqb : a == 1 ? Wkb : a == 2 ? Wvb : Wob;
    }
    f32x4 f = ((const f32x4*)s)[o];
    u32x2 v;
    v[0] = cvt_pk_bf16(f[0], f[1]);
    v[1] = cvt_pk_bf16(f[2], f[3]);
    ((u32x2*)d)[o] = v;
}

// ---- fused QKV GEMM: C[m][n] = sum_k A[m][k]*B[n][k]; per-block output select ----
// which = blockIdx.x>>3: 0->Q (scaled, [b,h,s,d]), 1->K ([b,h,s,d]), 2->V^T ([b,h,d,s])
__global__ __launch_bounds__(256) void gemm_qkv(const u16* __restrict__ A,
        const u16* __restrict__ B0, const u16* __restrict__ B1, const u16* __restrict__ B2,
        const float* __restrict__ c0, const float* __restrict__ c1, const float* __restrict__ c2,
        u16* __restrict__ O0, u16* __restrict__ O1, u16* __restrict__ O2) {
    __shared__ __align__(16) u16 As[2][128 * 64];
    __shared__ __align__(16) u16 Bs[2][128 * 64];
    const int tid  = threadIdx.x;
    const int w    = tid >> 6, lane = tid & 63;
    const int l15  = lane & 15, g = lane >> 4;
    const int wr   = w >> 1, wc = w & 1;
    const int which = blockIdx.x >> 3;
    const int bm0  = blockIdx.y * 128, bn0 = (blockIdx.x & 7) * 128;
    const u16* Bp     = which == 0 ? B0 : which == 1 ? B1 : B2;
    const float* bias = which == 0 ? c0 : which == 1 ? c1 : c2;
    u16* outp         = which == 0 ? O0 : which == 1 ? O1 : O2;
    const float scale = which == 0 ? 0.18033688011112042f : 1.0f;  // (1/8)*log2(e)

    // per-lane staging sources (chunk swizzled)
    const u16* asrc[4]; const u16* bsrc[4];
#pragma unroll
    for (int i = 0; i < 4; ++i) {
        int c = (w * 4 + i) * 64 + lane;
        int row = c >> 3, kc = (c & 7) ^ (row & 7);
        asrc[i] = A  + (size_t)(bm0 + row) * 1024 + kc * 8;
        bsrc[i] = Bp + (size_t)(bn0 + row) * 1024 + kc * 8;
    }
    auto stage = [&](int buf, int kt) {
#pragma unroll
        for (int i = 0; i < 4; ++i) {
            gload_lds16(asrc[i] + kt * 64, &As[buf][(w * 4 + i) * 512]);
            gload_lds16(bsrc[i] + kt * 64, &Bs[buf][(w * 4 + i) * 512]);
        }
    };

    f32x4 acc[4][4] = {};
    stage(0, 0);

#pragma unroll 2
    for (int kt = 0; kt < 16; ++kt) {
        const int cur = kt & 1;
        if (kt < 15) {
            stage(cur ^ 1, kt + 1);
            asm volatile("s_waitcnt vmcnt(8)" ::: "memory");
        } else {
            asm volatile("s_waitcnt vmcnt(0)" ::: "memory");
        }
        __builtin_amdgcn_s_barrier();
        __builtin_amdgcn_sched_barrier(0);

#pragma unroll
        for (int kk = 0; kk < 2; ++kk) {
            s16x8 af[4], bf_[4];
#pragma unroll
            for (int mi = 0; mi < 4; ++mi) {
                int row = wr * 64 + mi * 16 + l15;
                af[mi] = *(const s16x8*)&As[cur][row * 64 + (((kk * 4 + g) ^ (row & 7)) << 3)];
            }
#pragma unroll
            for (int ni = 0; ni < 4; ++ni) {
                int row = wc * 64 + ni * 16 + l15;
                bf_[ni] = *(const s16x8*)&Bs[cur][row * 64 + (((kk * 4 + g) ^ (row & 7)) << 3)];
            }
#pragma unroll
            for (int mi = 0; mi < 4; ++mi)
#pragma unroll
                for (int ni = 0; ni < 4; ++ni)
                    acc[mi][ni] = __builtin_amdgcn_mfma_f32_16x16x32_bf16(af[mi], bf_[ni], acc[mi][ni], 0, 0, 0);
        }
        __builtin_amdgcn_sched_barrier(0);
        __builtin_amdgcn_s_barrier();
    }

#pragma unroll
    for (int mi = 0; mi < 4; ++mi) {
#pragma unroll
        for (int ni = 0; ni < 4; ++ni) {
            int ncol = bn0 + wc * 64 + ni * 16 + l15;
            float bv = bias[ncol];
#pragma unroll
            for (int r = 0; r < 4; ++r) {
                int m   = bm0 + wr * 64 + mi * 16 + g * 4 + r;
                float v = (acc[mi][ni][r] + bv) * scale;
                int b_ = m >> 11, s = m & 2047, h = ncol >> 6, d = ncol & 63;
                if (which == 2)
                    outp[(((size_t)(b_ * 16 + h)) * 64 + d) * 2048 + s] = f2bf(v);
                else
                    outp[(((size_t)(b_ * 16 + h)) * 2048 + s) * 64 + d] = f2bf(v);
            }
        }
    }
}

// ---- output GEMM: f32 out, linear [m][n] ----
__global__ __launch_bounds__(256) void gemm_out(const u16* __restrict__ A, const u16* __restrict__ B,
                                                const float* __restrict__ bias, float* __restrict__ outp) {
    __shared__ __align__(16) u16 As[2][128 * 64];
    __shared__ __align__(16) u16 Bs[2][128 * 64];
    const int tid  = threadIdx.x;
    const int w    = tid >> 6, lane = tid & 63;
    const int l15  = lane & 15, g = lane >> 4;
    const int wr   = w >> 1, wc = w & 1;
    const int bm0  = blockIdx.y * 128, bn0 = blockIdx.x * 128;

    const u16* asrc[4]; const u16* bsrc[4];
#pragma unroll
    for (int i = 0; i < 4; ++i) {
        int c = (w * 4 + i) * 64 + lane;
        int row = c >> 3, kc = (c & 7) ^ (row & 7);
        asrc[i] = A + (size_t)(bm0 + row) * 1024 + kc * 8;
        bsrc[i] = B + (size_t)(bn0 + row) * 1024 + kc * 8;
    }
    auto stage = [&](int buf, int kt) {
#pragma unroll
        for (int i = 0; i < 4; ++i) {
            gload_lds16(asrc[i] + kt * 64, &As[buf][(w * 4 + i) * 512]);
            gload_lds16(bsrc[i] + kt * 64, &Bs[buf][(w * 4 + i) * 512]);
        }
    };

    f32x4 acc[4][4] = {};
    stage(0, 0);

#pragma unroll 2
    for (int kt = 0; kt < 16; ++kt) {
        const int cur = kt & 1;
        if (kt < 15) {
            stage(cur ^ 1, kt + 1);
            asm volatile("s_waitcnt vmcnt(8)" ::: "memory");
        } else {
            asm volatile("s_waitcnt vmcnt(0)" ::: "memory");
        }
        __builtin_amdgcn_s_barrier();
        __builtin_amdgcn_sched_barrier(0);

#pragma unroll
        for (int kk = 0; kk < 2; ++kk) {
            s16x8 af[4], bf_[4];
#pragma unroll
            for (int mi = 0; mi < 4; ++mi) {
                int row = wr * 64 + mi * 16 + l15;
                af[mi] = *(const s16x8*)&As[cur][row * 64 + (((kk * 4 + g) ^ (row & 7)) << 3)];
            }
#pragma unroll
            for (int ni = 0; ni < 4; ++ni) {
                int row = wc * 64 + ni * 16 + l15;
                bf_[ni] = *(const s16x8*)&Bs[cur][row * 64 + (((kk * 4 + g) ^ (row & 7)) << 3)];
            }
#pragma unroll
            for (int mi = 0; mi < 4; ++mi)
#pragma unroll
                for (int ni = 0; ni < 4; ++ni)
                    acc[mi][ni] = __builtin_amdgcn_mfma_f32_16x16x32_bf16(af[mi], bf_[ni], acc[mi][ni], 0, 0, 0);
        }
        __builtin_amdgcn_sched_barrier(0);
        __builtin_amdgcn_s_barrier();
    }

#pragma unroll
    for (int mi = 0; mi < 4; ++mi) {
#pragma unroll
        for (int ni = 0; ni < 4; ++ni) {
            int ncol = bn0 + wc * 64 + ni * 16 + l15;
            float bv = bias[ncol];
#pragma unroll
            for (int r = 0; r < 4; ++r) {
                int m = bm0 + wr * 64 + mi * 16 + g * 4 + r;
                outp[(size_t)m * 1024 + ncol] = acc[mi][ni][r] + bv;
            }
        }
    }
}

// ---- flash attention, swapped-operand, 2-phase pipelined ----
__global__ __launch_bounds__(256) void attn_kernel(const u16* __restrict__ Q, const u16* __restrict__ K,
                                                   const u16* __restrict__ VT, u16* __restrict__ C) {
    __shared__ __align__(16) u16 Ks[2][64 * 64];
    __shared__ __align__(16) u16 Vs[2][64 * 64];
    __shared__ __align__(16) u16 Ps[4][16 * 64];
    const int tid = threadIdx.x;
    const int w   = tid >> 6, lane = tid & 63;
    const int l15 = lane & 15, g = lane >> 4;
    const int bh  = blockIdx.x >> 5;
    const int qt  = blockIdx.x & 31;
    const u16* Qb = Q  + (size_t)bh * 2048 * 64;
    const u16* Kb = K  + (size_t)bh * 2048 * 64;
    const u16* Vb = VT + (size_t)bh * 64 * 2048;
    const int q0  = qt * 64 + w * 16;

    // Q rows as B-fragments (col=q)
    s16x8 bq[2];
#pragma unroll
    for (int kk = 0; kk < 2; ++kk)
        bq[kk] = *(const s16x8*)&Qb[(size_t)(q0 + l15) * 64 + kk * 32 + g * 8];

    // per-lane staging sources (chunk swizzled)
    const u16* ksrc[2]; const u16* vsrc[2];
#pragma unroll
    for (int i = 0; i < 2; ++i) {
        int c = w * 128 + i * 64 + lane;
        int rt = c >> 3, cc = (c & 7) ^ (rt & 7);
        ksrc[i] = Kb + (size_t)rt * 64 + cc * 8;
        vsrc[i] = Vb + (size_t)rt * 2048 + cc * 8;
    }
    auto stage = [&](int buf, int kt) {
        int kb = kt * 64;
#pragma unroll
        for (int i = 0; i < 2; ++i) {
            gload_lds16(ksrc[i] + (size_t)kb * 64, &Ks[buf][(w * 128 + i * 64) * 8]);
            gload_lds16(vsrc[i] + kb,              &Vs[buf][(w * 128 + i * 64) * 8]);
        }
    };

    float m_ = -1e30f, l_ = 0.f;
    f32x4 accO[4] = {};
    stage(0, 0);

#pragma unroll 2
    for (int kt = 0; kt < 32; ++kt) {
        const int cur = kt & 1;
        if (kt < 31) {
            stage(cur ^ 1, kt + 1);
            asm volatile("s_waitcnt vmcnt(4)" ::: "memory");
        } else {
            asm volatile("s_waitcnt vmcnt(0)" ::: "memory");
        }
        __builtin_amdgcn_s_barrier();
        __builtin_amdgcn_sched_barrier(0);

        // S^T = K . Q^T : lane holds S[q=l15][k = kj*16 + g*4 + r]
        f32x4 sc[4];
#pragma unroll
        for (int kj = 0; kj < 4; ++kj) {
            f32x4 z = {};
#pragma unroll
            for (int kk = 0; kk < 2; ++kk) {
                int row  = kj * 16 + l15;
                s16x8 ak = *(const s16x8*)&Ks[cur][row * 64 + (((kk * 4 + g) ^ (l15 & 7)) << 3)];
                z = __builtin_amdgcn_mfma_f32_16x16x32_bf16(ak, bq[kk], z, 0, 0, 0);
            }
            sc[kj] = z;
        }

        // online softmax (exp2 domain), row q=l15 lane-local
        float t0 = fmaxf(fmaxf(sc[0][0], sc[0][1]), fmaxf(sc[0][2], sc[0][3]));
        float t1 = fmaxf(fmaxf(sc[1][0], sc[1][1]), fmaxf(sc[1][2], sc[1][3]));
        float t2 = fmaxf(fmaxf(sc[2][0], sc[2][1]), fmaxf(sc[2][2], sc[2][3]));
        float t3 = fmaxf(fmaxf(sc[3][0], sc[3][1]), fmaxf(sc[3][2], sc[3][3]));
        float t  = fmaxf(fmaxf(t0, t1), fmaxf(t2, t3));
        t = fmaxf(t, __shfl_xor(t, 16));
        t = fmaxf(t, __shfl_xor(t, 32));

        const bool grow = __any(t > m_);   // wave-uniform; exact skip when false
        if (grow) {
            float mn    = fmaxf(m_, t);
            float alpha = __builtin_amdgcn_exp2f(m_ - mn);
            m_ = mn;
            l_ *= alpha;
#pragma unroll
            for (int jd = 0; jd < 4; ++jd)
#pragma unroll
                for (int r = 0; r < 4; ++r) accO[jd][r] *= alpha;
        }

        float p[4][4], ps = 0.f;
#pragma unroll
        for (int kj = 0; kj < 4; ++kj)
#pragma unroll
            for (int r = 0; r < 4; ++r) {
                p[kj][r] = __builtin_amdgcn_exp2f(sc[kj][r] - m_);
                ps += p[kj][r];
            }
        ps += __shfl_xor(ps, 16);
        ps += __shfl_xor(ps, 32);
        l_ += ps;

        // P -> LDS (per-wave private), packed b64 writes, chunk XOR swizzle
#pragma unroll
        for (int kj = 0; kj < 4; ++kj) {
            int cs = (kj * 4 + g) ^ ((l15 & 7) << 1);
            u32x2 v;
            v[0] = cvt_pk_bf16(p[kj][0], p[kj][1]);
            v[1] = cvt_pk_bf16(p[kj][2], p[kj][3]);
            *(u32x2*)&Ps[w][l15 * 64 + cs * 4] = v;
        }

        // P fragments back (B-frag: row q=l15, k-slice)
        s16x8 pf[2];
#pragma unroll
        for (int kk = 0; kk < 2; ++kk) {
            int c0 = (kk * 8 + g * 2) ^ ((l15 & 7) << 1);
            pf[kk] = *(const s16x8*)&Ps[w][l15 * 64 + c0 * 4];
        }

        // O^T += V^T . P^T
#pragma unroll
        for (int jd = 0; jd < 4; ++jd) {
#pragma unroll
            for (int kk = 0; kk < 2; ++kk) {
                int row  = jd * 16 + l15;
                s16x8 av = *(const s16x8*)&Vs[cur][row * 64 + (((kk * 4 + g) ^ (l15 & 7)) << 3)];
                accO[jd] = __builtin_amdgcn_mfma_f32_16x16x32_bf16(av, pf[kk], accO[jd], 0, 0, 0);
            }
        }
        __builtin_amdgcn_sched_barrier(0);
        __builtin_amdgcn_s_barrier();
    }

    const int b_ = bh >> 4, h = bh & 15;
    const int s  = q0 + l15;
    float inv    = 1.0f / l_;
#pragma unroll
    for (int jd = 0; jd < 4; ++jd) {
        u32x2 v;
        v[0] = cvt_pk_bf16(accO[jd][0] * inv, accO[jd][1] * inv);
        v[1] = cvt_pk_bf16(accO[jd][2] * inv, accO[jd][3] * inv);
        *(u32x2*)&C[((size_t)(b_ * 2048 + s)) * 1024 + h * 64 + jd * 16 + g * 4] = v;
    }
}

extern "C" void kernel_launch(void* const* d_in, const int* in_sizes, int n_in,
                              void* d_out, int out_size, void* d_ws, size_t ws_size,
                              hipStream_t stream) {
    const float* H  = (const float*)d_in[0];
    const float* Wq = (const float*)d_in[1];
    const float* bq = (const float*)d_in[2];
    const float* Wk = (const float*)d_in[3];
    const float* bk = (const float*)d_in[4];
    const float* Wv = (const float*)d_in[5];
    const float* bv = (const float*)d_in[6];
    const float* Wo = (const float*)d_in[7];
    const float* bo = (const float*)d_in[8];

    char*  ws  = (char*)d_ws;
    size_t off = 0;
    auto alloc = [&](size_t elems) { u16* p = (u16*)(ws + off); off += elems * 2; return p; };
    u16* Hb  = alloc((size_t)8192 * 1024);
    u16* Wqb = alloc((size_t)1024 * 1024);
    u16* Wkb = alloc((size_t)1024 * 1024);
    u16* Wvb = alloc((size_t)1024 * 1024);
    u16* Wob = alloc((size_t)1024 * 1024);
    u16* Qs  = alloc((size_t)8192 * 1024);
    u16* Ks  = alloc((size_t)8192 * 1024);
    u16* VTs = alloc((size_t)8192 * 1024);
    u16* Cc  = alloc((size_t)8192 * 1024);

    cvt_all<<<12288, 256, 0, stream>>>(H, Wq, Wk, Wv, Wo, Hb, Wqb, Wkb, Wvb, Wob);

    dim3 gq(24, 64);
    gemm_qkv<<<gq, 256, 0, stream>>>(Hb, Wqb, Wkb, Wvb, bq, bk, bv, Qs, Ks, VTs);

    attn_kernel<<<2048, 256, 0, stream>>>(Qs, Ks, VTs, Cc);

    dim3 gg(8, 64);
    gemm_out<<<gg, 256, 0, stream>>>(Cc, Wob, bo, (float*)d_out);
}